// Round 4
// baseline (828.699 us; speedup 1.0000x reference)
//
#include <hip/hip_runtime.h>

// ---------- helpers ----------
typedef __bf16 bf16x8 __attribute__((ext_vector_type(8)));
typedef float  f32x4  __attribute__((ext_vector_type(4)));

static __device__ __forceinline__ unsigned short f32_to_bf16(float f) {
  union { float f; unsigned u; } v; v.f = f;
  unsigned r = v.u + 0x7fffu + ((v.u >> 16) & 1u);   // RNE
  return (unsigned short)(r >> 16);
}

// LDS bank swizzle: rows are 128 B (exactly one bank sweep), so bank depends only on
// chunk mod 8. Mix row bits 0-2, 4-6, 7+ into the chunk slot; verified <=2 lanes per
// bank-group for all read/write patterns below.
static __device__ __forceinline__ int swz(int row) {
  return (row ^ (row >> 4) ^ (row >> 7)) & 7;
}

// ---------- L,R f32 -> bf16 (natural layouts are MFMA-A-friendly) ----------
__global__ __launch_bounds__(256) void k_cvt2(const float* __restrict__ L,
                                              const float* __restrict__ R,
                                              unsigned short* __restrict__ Lb,
                                              unsigned short* __restrict__ Rb) {
  int i = blockIdx.x * 256 + threadIdx.x;
  const float* s; unsigned short* d; int idx;
  if (i < 524288) { s = L; d = Lb; idx = i; } else { s = R; d = Rb; idx = i - 524288; }
  float4 v = ((const float4*)s)[idx];
  uint2 o;
  o.x = (unsigned)f32_to_bf16(v.x) | ((unsigned)f32_to_bf16(v.y) << 16);
  o.y = (unsigned)f32_to_bf16(v.z) | ((unsigned)f32_to_bf16(v.w) << 16);
  ((uint2*)d)[idx] = o;
}

// ---------- Stage A ----------
// T[j][r][m] = sum_k L[m][j][k] * x[r][k*128+m]
// Block: m-tile 16, r-tile 16, j-half 64 (4 waves x 16 j). 32 KiB LDS, 2 k-half rounds.
// MFMA M=j (A = L from L2, natural), N=r (B = Xs LDS). Lane packs 16 m -> 32 B T store;
// m-chunk pairs and j-half pairs are co-XCD'd via bid decode for L2 line merge / reuse.
__global__ __launch_bounds__(256, 4) void k_stageA(const float* __restrict__ x,
                                                   const unsigned short* __restrict__ Lb,
                                                   unsigned short* __restrict__ T) {
  __shared__ unsigned short Xs[16 * 16 * 64];   // [m16][r16][k64] bf16, 32 KiB, swizzled
  const int bid = blockIdx.x;
  const int u = bid & 7, jh = (bid >> 3) & 1, mh = (bid >> 4) & 1;
  const int rest = bid >> 5;                    // 0..127
  const int mc = rest & 3, rtt = rest >> 2;     // m-chunk-pair, r-tile group
  const int r0 = (rtt * 8 + u) << 4;
  const int m0 = ((mc << 1) + mh) << 4;
  const int tid = threadIdx.x;
  const int w = tid >> 6, lane = tid & 63;
  const int l16 = lane & 15, q = lane >> 4;
  const int j0w = ((jh << 2) + w) << 4;

  const int mg = tid & 3, rq = (tid >> 2) & 3, kg = tid >> 4;   // staging map, kg 0..15
  f32x4 acc[16] = {};
  const unsigned short* Lbase = Lb + (size_t)m0 * 16384 + ((j0w + l16) << 7) + (q << 3);

#pragma unroll
  for (int kr = 0; kr < 2; ++kr) {
    if (kr) __syncthreads();                    // all reads of Xs done before restage
    // stage x[r0..+15][(kr*64+kl)*128 + m0..+15] -> Xs[m][r][kl], bf16 + micro-transpose
#pragma unroll
    for (int rr = 0; rr < 4; ++rr) {
      const int r = (rr << 2) + rq;
      const float* g = x + (size_t)(r0 + r) * 16384 + ((kr << 6) + (kg << 2)) * 128 + m0 + (mg << 2);
      float4 v0 = *(const float4*)(g);
      float4 v1 = *(const float4*)(g + 128);
      float4 v2 = *(const float4*)(g + 256);
      float4 v3 = *(const float4*)(g + 384);
#pragma unroll
      for (int mm = 0; mm < 4; ++mm) {
        const int row = (((mg << 2) + mm) << 4) + r;
        unsigned short o[4] = { f32_to_bf16(((const float*)&v0)[mm]),
                                f32_to_bf16(((const float*)&v1)[mm]),
                                f32_to_bf16(((const float*)&v2)[mm]),
                                f32_to_bf16(((const float*)&v3)[mm]) };
        *(uint2*)((char*)Xs + row * 128 + (((kg >> 1) ^ swz(row)) << 4) + ((kg & 1) << 3)) =
            *(const uint2*)o;
      }
    }
    __syncthreads();
    // MFMA over this k-half
#pragma unroll
    for (int ksl = 0; ksl < 2; ++ksl) {
#pragma unroll
      for (int mb = 0; mb < 16; ++mb) {
        const bf16x8 af = *(const bf16x8*)(Lbase + (size_t)mb * 16384 + (kr << 6) + (ksl << 5));
        const int row = (mb << 4) + l16;
        const bf16x8 bf = *(const bf16x8*)((const char*)Xs + row * 128
                                           + ((((ksl << 2) + q) ^ swz(row)) << 4));
        acc[mb] = __builtin_amdgcn_mfma_f32_16x16x32_bf16(af, bf, acc[mb], 0, 0, 0);
      }
    }
  }
  // store: lane (l16=r, q), p: j = j0w + q*4 + p; 16 m bf16 = 32 B contiguous
#pragma unroll
  for (int p = 0; p < 4; ++p) {
    const int j = j0w + (q << 2) + p;
    unsigned short o[16];
#pragma unroll
    for (int mb = 0; mb < 16; ++mb) o[mb] = f32_to_bf16(acc[mb][p]);
    unsigned short* tp = T + (size_t)j * 524288 + ((size_t)(r0 + l16) << 7) + m0;
    *(uint4*)tp = *(const uint4*)o;
    *(uint4*)(tp + 8) = *(const uint4*)(o + 8);
  }
}

// ---------- Stage B ----------
// out[r][i*128+j] = sum_m R[j][i][m] * T[j][r][m] + bias
// Block: j-tile 16 (bid&7 -> XCD R-affinity), r-tile 16, i full (8 waves x 16).
// 32 KiB LDS, 2 m-half rounds; staging is a pure contiguous copy (T is m-innermost).
// MFMA M=i (A = R from L2, natural), N=r (B = Ts). Lane owns a full 64 B out line.
__global__ __launch_bounds__(512, 4) void k_stageB(const unsigned short* __restrict__ T,
                                                   const unsigned short* __restrict__ Rb,
                                                   const float* __restrict__ bias,
                                                   float* __restrict__ out) {
  __shared__ unsigned short Ts[16 * 16 * 64];   // [j16][r16][m64] bf16, 32 KiB, swizzled
  const int bid = blockIdx.x;
  const int j0 = (bid & 7) << 4;
  const int r0 = (bid >> 3) << 4;
  const int tid = threadIdx.x;
  const int w = tid >> 6, lane = tid & 63;
  const int l16 = lane & 15, q = lane >> 4;
  const int ib = w << 4;

  f32x4 acc[16] = {};
  const unsigned short* Rbase = Rb + (size_t)j0 * 16384 + ((ib + l16) << 7) + (q << 3);

#pragma unroll
  for (int mr = 0; mr < 2; ++mr) {
    if (mr) __syncthreads();
    // stage T[j0..+15][r0..+15][mr*64..+63] -> Ts (contiguous 128 B per (j,r) row)
#pragma unroll
    for (int it = 0; it < 4; ++it) {
      const int flat = (it << 9) + tid;         // 0..2047
      const int c8 = flat & 7, r = (flat >> 3) & 15, jj = flat >> 7;
      const uint4 v = *(const uint4*)(T + (size_t)(j0 + jj) * 524288
                                      + ((size_t)(r0 + r) << 7) + (mr << 6) + (c8 << 3));
      const int row = (jj << 4) + r;
      *(uint4*)((char*)Ts + row * 128 + ((c8 ^ swz(row)) << 4)) = v;
    }
    __syncthreads();
#pragma unroll
    for (int msl = 0; msl < 2; ++msl) {
#pragma unroll
      for (int jb = 0; jb < 16; ++jb) {
        const bf16x8 af = *(const bf16x8*)(Rbase + (size_t)jb * 16384 + (mr << 6) + (msl << 5));
        const int row = (jb << 4) + l16;
        const bf16x8 bf = *(const bf16x8*)((const char*)Ts + row * 128
                                           + ((((msl << 2) + q) ^ swz(row)) << 4));
        acc[jb] = __builtin_amdgcn_mfma_f32_16x16x32_bf16(af, bf, acc[jb], 0, 0, 0);
      }
    }
  }
  // epilogue: lane (l16=r, q), p: i = ib + q*4 + p; full 64 B line with fused bias
#pragma unroll
  for (int p = 0; p < 4; ++p) {
    const int i = ib + (q << 2) + p;
    const float* bp = bias + (i << 7) + j0;
    float* op = out + ((size_t)(r0 + l16) << 14) + (i << 7) + j0;
#pragma unroll
    for (int g4 = 0; g4 < 4; ++g4) {
      float4 b = *(const float4*)(bp + (g4 << 2));
      float4 o;
      o.x = acc[(g4 << 2) + 0][p] + b.x;
      o.y = acc[(g4 << 2) + 1][p] + b.y;
      o.z = acc[(g4 << 2) + 2][p] + b.z;
      o.w = acc[(g4 << 2) + 3][p] + b.w;
      *(float4*)(op + (g4 << 2)) = o;
    }
  }
}

extern "C" void kernel_launch(void* const* d_in, const int* in_sizes, int n_in,
                              void* d_out, int out_size, void* d_ws, size_t ws_size,
                              hipStream_t stream) {
  const float* x    = (const float*)d_in[0];   // 4096 x 16384 f32
  const float* L    = (const float*)d_in[1];   // 128^3 f32  [m][j][k]
  const float* R    = (const float*)d_in[2];   // 128^3 f32  [j][i][m]
  const float* bias = (const float*)d_in[3];   // 16384 f32
  float* out = (float*)d_out;

  // workspace: Lb 4M | Rb 4M | T 128M  (T[j][r][m] bf16)
  const size_t SZ_W = (size_t)4 << 20;
  const size_t SZ_T = (size_t)128 << 20;
  if (ws_size < 2 * SZ_W + SZ_T) return;       // fail loudly (poison stays)

  char* ws = (char*)d_ws;
  unsigned short* Lb = (unsigned short*)ws;
  unsigned short* Rb = (unsigned short*)(ws + SZ_W);
  unsigned short* Tw = (unsigned short*)(ws + 2 * SZ_W);

  k_cvt2<<<4096, 256, 0, stream>>>(L, R, Lb, Rb);
  k_stageA<<<4096, 256, 0, stream>>>(x, Lb, Tw);          // 8 m x 256 r x 2 j-half
  k_stageB<<<2048, 512, 0, stream>>>(Tw, Rb, bias, out);  // 8 j x 256 r
}